// Round 1
// baseline (7143.905 us; speedup 1.0000x reference)
//
#include <hip/hip_runtime.h>
#include <type_traits>

constexpr int NN = 5000;   // nodes
constexpr int NP = 5120;   // padded nodes / K
constexpr int TT = 12;     // enc/dec length
constexpr int UU = 32;     // rnn units
constexpr int FP = 48;     // padded feature rows
constexpr int FR = 33;     // real feature rows (IN+U)
constexpr int DN = 99;     // DIN
constexpr int BN = 32;     // nodes per block
constexpr int KC = 128;    // K chunk
constexpr int NKC = NP / KC;                 // 40
constexpr int GRID_MM = (NN + BN - 1) / BN;  // 157

typedef __attribute__((ext_vector_type(8))) short short8;
typedef __attribute__((ext_vector_type(4))) float f32x4;

__device__ __forceinline__ unsigned short f2bf(float x) {
  union { float f; unsigned u; } c; c.f = x;
  return (unsigned short)((c.u + 0x7FFFu + ((c.u >> 16) & 1u)) >> 16);
}

__global__ void k_zero(uint4* __restrict__ p, int n) {
  int i = blockIdx.x * 256 + threadIdx.x;
  if (i < n) p[i] = make_uint4(0u, 0u, 0u, 0u);
}

__global__ void k_cast(const float* __restrict__ adj, unsigned short* __restrict__ adjb) {
  int col = (blockIdx.x * 256 + threadIdx.x) * 4;
  int row = blockIdx.y;
  float4 v = make_float4(0.f, 0.f, 0.f, 0.f);
  if (col < NN) v = *(const float4*)(adj + (size_t)row * NN + col);
  uint2 o;
  o.x = (unsigned)f2bf(v.x) | ((unsigned)f2bf(v.y) << 16);
  o.y = (unsigned)f2bf(v.z) | ((unsigned)f2bf(v.w) << 16);
  *(uint2*)(adjb + (size_t)row * NP + col) = o;
}

__global__ void k_initx0(const float* __restrict__ in, float* __restrict__ xf,
                         unsigned short* __restrict__ xb) {
  int n = blockIdx.x * 256 + threadIdx.x;
  if (n >= NP) return;
  float v = (n < NN) ? in[(size_t)n * TT] : 0.f;
  xf[n] = v; xb[n] = f2bf(v);
}

// C^T[f 0..47][node] = sum_k rhs^T[f][k] * A[node][k]
// waves 0,1: MFMA consumers (wave w -> nodes nodeBase + w*16 + m)
// waves 2,3: LDS stagers (double-buffered X^T chunk)
// EPI: 0 = store x1 (f32 + bf16); 1 = gate epilogue; 2 = candidate epilogue
template <int EPI, bool USEBF>
__global__ __launch_bounds__(256) void k_gemm(
    const unsigned short* __restrict__ adjb, const float* __restrict__ adjf,
    const unsigned short* __restrict__ rhs,
    float* __restrict__ outF, unsigned short* __restrict__ outB,
    const float* __restrict__ s0F, const float* __restrict__ s1F,
    const float* __restrict__ W, const float* __restrict__ bias,
    float* __restrict__ hT, float* __restrict__ uT,
    float* __restrict__ xoF, unsigned short* __restrict__ xoB,
    const float* __restrict__ inp, const float* __restrict__ Wp,
    const float* __restrict__ bp, float* __restrict__ dout,
    int mode, int tnext, int dstep) {
  constexpr int WC = (EPI == 1) ? 64 : 32;
  __shared__ __align__(16) unsigned short Xs[2][FP][136];  // 272B rows: 2-way max conflict
  __shared__ float x2s[(EPI > 0) ? FP : 1][(EPI > 0) ? 36 : 1];
  __shared__ float Ws[(EPI > 0) ? DN * WC : 1];

  const int tid = threadIdx.x;
  const int wave = tid >> 6;
  const int lane = tid & 63;
  const int m = lane & 15;
  const int q = lane >> 4;
  const int nodeBase = blockIdx.x * BN;

  if constexpr (EPI > 0) {
    for (int i = tid; i < DN * WC; i += 256) Ws[i] = W[i];
  }

  f32x4 acc[3] = {};
  int gn = nodeBase + wave * 16 + m;                 // consumer node (waves 0,1)
  size_t ar = (size_t)((gn < NN) ? gn : NN - 1);     // clamped adj row

  if (wave >= 2) {  // stage chunk 0 into buf 0
    int t2 = tid - 128;
    for (int r = 0; r < 6; ++r) {
      int idx = r * 128 + t2;
      int row = idx >> 4, seg = idx & 15;
      *(uint4*)(&Xs[0][row][seg * 8]) = *(const uint4*)(rhs + (size_t)row * NP + seg * 8);
    }
  }

  for (int kc = 0; kc < NKC; ++kc) {
    __syncthreads();
    if (wave >= 2) {
      if (kc + 1 < NKC) {
        int k0 = (kc + 1) * KC;
        int t2 = tid - 128;
        int buf = (kc + 1) & 1;
        for (int r = 0; r < 6; ++r) {
          int idx = r * 128 + t2;
          int row = idx >> 4, seg = idx & 15;
          *(uint4*)(&Xs[buf][row][seg * 8]) =
              *(const uint4*)(rhs + (size_t)row * NP + k0 + seg * 8);
        }
      }
    } else {
      const int k0 = kc * KC;
      const int buf = kc & 1;
      short8 bfr[4];
      if (USEBF) {
        const unsigned short* a0 = adjb + ar * NP + k0 + q * 8;
#pragma unroll
        for (int ks = 0; ks < 4; ++ks) bfr[ks] = *(const short8*)(a0 + ks * 32);
      } else {
        const float* a0 = adjf + ar * NN;
#pragma unroll
        for (int ks = 0; ks < 4; ++ks) {
          int kb = k0 + ks * 32 + q * 8;
          union { short8 s; unsigned short u[8]; } p0;
          if (kb + 8 <= NN) {
            float4 x0 = *(const float4*)(a0 + kb);
            float4 x1 = *(const float4*)(a0 + kb + 4);
            p0.u[0] = f2bf(x0.x); p0.u[1] = f2bf(x0.y); p0.u[2] = f2bf(x0.z); p0.u[3] = f2bf(x0.w);
            p0.u[4] = f2bf(x1.x); p0.u[5] = f2bf(x1.y); p0.u[6] = f2bf(x1.z); p0.u[7] = f2bf(x1.w);
          } else {
            for (int j = 0; j < 8; ++j) {
              int k = kb + j;
              p0.u[j] = (k < NN) ? f2bf(a0[k]) : (unsigned short)0;
            }
          }
          bfr[ks] = p0.s;
        }
      }
#pragma unroll
      for (int ks = 0; ks < 4; ++ks) {
#pragma unroll
        for (int t3 = 0; t3 < 3; ++t3) {
          short8 af = *(const short8*)(&Xs[buf][m + 16 * t3][ks * 32 + q * 8]);
          acc[t3] = __builtin_amdgcn_mfma_f32_16x16x32_bf16(af, bfr[ks], acc[t3], 0, 0, 0);
        }
      }
    }
  }

  if constexpr (EPI == 0) {
    if (wave < 2) {
      bool v = gn < NN;
#pragma unroll
      for (int t3 = 0; t3 < 3; ++t3)
#pragma unroll
        for (int r = 0; r < 4; ++r) {
          int f = t3 * 16 + q * 4 + r;  // C/D: row = (lane>>4)*4 + reg
          float val = v ? acc[t3][r] : 0.f;
          outF[(size_t)f * NP + gn] = val;
          outB[(size_t)f * NP + gn] = f2bf(val);
        }
    }
  } else {
    if (wave < 2) {
#pragma unroll
      for (int t3 = 0; t3 < 3; ++t3)
#pragma unroll
        for (int r = 0; r < 4; ++r)
          x2s[t3 * 16 + q * 4 + r][wave * 16 + m] = acc[t3][r];
    }
    __syncthreads();
    const int nl = tid & 31;
    const int cg = tid >> 5;  // 0..7
    const int gn2 = nodeBase + nl;
    const bool valid = gn2 < NN;
    const int gnc = valid ? gn2 : NN - 1;
    constexpr int NI = (EPI == 1) ? 8 : 4;  // cols = cg + 8*i
    float accd[NI];
#pragma unroll
    for (int i = 0; i < NI; ++i) accd[i] = bias[cg + 8 * i];
    for (int f = 0; f < FR; ++f) {
      float fe = s0F[(size_t)f * NP + gnc];
#pragma unroll
      for (int i = 0; i < NI; ++i) accd[i] += fe * Ws[f * WC + cg + 8 * i];
    }
    for (int f = 0; f < FR; ++f) {
      float fe = s1F[(size_t)f * NP + gnc];
#pragma unroll
      for (int i = 0; i < NI; ++i) accd[i] += fe * Ws[(FR + f) * WC + cg + 8 * i];
    }
    for (int f = 0; f < FR; ++f) {
      float fe = x2s[f][nl];
#pragma unroll
      for (int i = 0; i < NI; ++i) accd[i] += fe * Ws[(2 * FR + f) * WC + cg + 8 * i];
    }
    if constexpr (EPI == 1) {
#pragma unroll
      for (int i = 0; i < NI; ++i) {
        int col = cg + 8 * i;
        float s = 1.f / (1.f + expf(-accd[i]));
        if (col < UU) {  // r gate -> xh_c row (1+col) = r*h
          float hv = hT[(size_t)col * NP + gnc];
          float xc = valid ? s * hv : 0.f;
          xoF[(size_t)(1 + col) * NP + gn2] = xc;
          xoB[(size_t)(1 + col) * NP + gn2] = f2bf(xc);
        } else {  // u gate
          uT[(size_t)(col - UU) * NP + gn2] = valid ? s : 0.f;
        }
      }
      if (tid < 32) {  // copy x row
        float v0 = s0F[gn2];
        xoF[gn2] = v0; xoB[gn2] = f2bf(v0);
      }
    } else {
      __syncthreads();  // all x2s reads done before reuse as hs
      float* hs = &x2s[0][0];
#pragma unroll
      for (int i = 0; i < NI; ++i) {
        int col = cg + 8 * i;  // 0..31
        float c = tanhf(accd[i]);
        float u = uT[(size_t)col * NP + gnc];
        float h0 = hT[(size_t)col * NP + gnc];
        float hn = u * h0 + (1.f - u) * c;
        float hw = valid ? hn : 0.f;
        hT[(size_t)col * NP + gn2] = hw;
        hs[col * 36 + nl] = hw;
        xoF[(size_t)(1 + col) * NP + gn2] = hw;
        xoB[(size_t)(1 + col) * NP + gn2] = f2bf(hw);
      }
      __syncthreads();
      if (tid < 32) {
        float x0 = 0.f;
        if (mode == 0) {
          x0 = valid ? inp[(size_t)gn2 * TT + tnext] : 0.f;
        } else if (mode == 2) {
          float p = bp[0];
          for (int j = 0; j < UU; ++j) p += hs[j * 36 + nl] * Wp[j];
          if (valid) dout[(size_t)gn2 * TT + dstep] = p;
          x0 = valid ? p : 0.f;
        }
        xoF[gn2] = x0; xoB[gn2] = f2bf(x0);
      }
    }
  }
}

extern "C" void kernel_launch(void* const* d_in, const int* in_sizes, int n_in,
                              void* d_out, int out_size, void* d_ws, size_t ws_size,
                              hipStream_t stream) {
  const float* inputs = (const float*)d_in[0];
  const float* adj = (const float*)d_in[2];
  const float* eWg = (const float*)d_in[3];
  const float* eBg = (const float*)d_in[4];
  const float* eWc = (const float*)d_in[5];
  const float* eBc = (const float*)d_in[6];
  const float* dWg = (const float*)d_in[7];
  const float* dBg = (const float*)d_in[8];
  const float* dWc = (const float*)d_in[9];
  const float* dBc = (const float*)d_in[10];
  const float* Wp = (const float*)d_in[11];
  const float* bp = (const float*)d_in[12];
  float* dout = (float*)d_out;

  char* ws = (char*)d_ws;
  size_t o = 0;
  float* xhGf = (float*)(ws + o); o += (size_t)FP * NP * 4;
  unsigned short* xhGb = (unsigned short*)(ws + o); o += (size_t)FP * NP * 2;
  float* xhCf = (float*)(ws + o); o += (size_t)FP * NP * 4;
  unsigned short* xhCb = (unsigned short*)(ws + o); o += (size_t)FP * NP * 2;
  float* x1f = (float*)(ws + o); o += (size_t)FP * NP * 4;
  unsigned short* x1b = (unsigned short*)(ws + o); o += (size_t)FP * NP * 2;
  float* hT = (float*)(ws + o); o += (size_t)UU * NP * 4;
  float* uT = (float*)(ws + o); o += (size_t)UU * NP * 4;
  size_t small = o;
  unsigned short* adjb = (unsigned short*)(ws + o);
  size_t need = o + (size_t)NN * NP * 2;
  bool usebf = ws_size >= need;

  k_zero<<<(int)(small / 16 / 256), 256, 0, stream>>>((uint4*)ws, (int)(small / 16));
  if (usebf) k_cast<<<dim3(5, NN), 256, 0, stream>>>(adj, adjb);
  k_initx0<<<NP / 256, 256, 0, stream>>>(inputs, xhGf, xhGb);

  auto run = [&](auto ubc) {
    constexpr bool UB = decltype(ubc)::value;
    const unsigned short* ab = UB ? adjb : nullptr;
    for (int t = 0; t < 2 * TT; ++t) {
      bool enc = t < TT;
      const float* Wg = enc ? eWg : dWg;
      const float* Bg = enc ? eBg : dBg;
      const float* Wc = enc ? eWc : dWc;
      const float* Bc = enc ? eBc : dBc;
      int mode, tn = 0, ds = 0;
      if (t < TT - 1) { mode = 0; tn = t + 1; }
      else if (t == TT - 1) { mode = 1; }
      else { mode = 2; ds = t - TT; }

      // K1: x1_g = A @ xh_g
      k_gemm<0, UB><<<GRID_MM, 256, 0, stream>>>(
          ab, adj, xhGb, x1f, x1b,
          nullptr, nullptr, nullptr, nullptr, nullptr, nullptr,
          nullptr, nullptr, nullptr, nullptr, nullptr, nullptr, 0, 0, 0);
      // K2: x2_g = A @ x1_g ; gate epilogue -> xh_c, u
      k_gemm<1, UB><<<GRID_MM, 256, 0, stream>>>(
          ab, adj, x1b, nullptr, nullptr,
          xhGf, x1f, Wg, Bg, hT, uT, xhCf, xhCb,
          nullptr, nullptr, nullptr, nullptr, 0, 0, 0);
      // K3: x1_c = A @ xh_c
      k_gemm<0, UB><<<GRID_MM, 256, 0, stream>>>(
          ab, adj, xhCb, x1f, x1b,
          nullptr, nullptr, nullptr, nullptr, nullptr, nullptr,
          nullptr, nullptr, nullptr, nullptr, nullptr, nullptr, 0, 0, 0);
      // K4: x2_c = A @ x1_c ; candidate epilogue -> h, next xh_g (+ projection)
      k_gemm<2, UB><<<GRID_MM, 256, 0, stream>>>(
          ab, adj, x1b, nullptr, nullptr,
          xhCf, x1f, Wc, Bc, hT, uT, xhGf, xhGb,
          inputs, Wp, bp, dout, mode, tn, ds);
    }
  };
  if (usebf) run(std::integral_constant<bool, true>{});
  else run(std::integral_constant<bool, false>{});
}

// Round 2
// 2493.373 us; speedup vs baseline: 2.8652x; 2.8652x over previous
//
#include <hip/hip_runtime.h>
#include <type_traits>

constexpr int NN = 5000;   // nodes
constexpr int NP = 5120;   // padded nodes / K
constexpr int TT = 12;     // enc/dec length
constexpr int UU = 32;     // rnn units
constexpr int FP = 48;     // padded feature rows
constexpr int FR = 33;     // real feature rows (IN+U)
constexpr int DN = 99;     // DIN
constexpr int BN = 16;     // nodes per block
constexpr int KC = 128;    // K chunk
constexpr int NKC = NP / KC;                 // 40
constexpr int CPW = NKC / 8;                 // 5 chunks per wave (8 waves split K)
constexpr int GRID_MM = (NN + BN - 1) / BN;  // 313
constexpr int CHE = FP * KC;                 // 6144 elements per chunk (frag layout)

typedef __attribute__((ext_vector_type(8))) short short8;
typedef __attribute__((ext_vector_type(4))) float f32x4;

__device__ __forceinline__ unsigned short f2bf(float x) {
  union { float f; unsigned u; } c; c.f = x;
  return (unsigned short)((c.u + 0x7FFFu + ((c.u >> 16) & 1u)) >> 16);
}

// MFMA A-fragment layout for X^T: element (f, node) ->
// chunk=node/128, ks=(node%128)/32, q=(node%8..), lane=m+16q, so a wave's
// 16B load at base+lane*16 is fully coalesced.
__device__ __forceinline__ int flatXF(int f, int node) {
  int chunk = node >> 7;
  int ks = (node >> 5) & 3;
  int q = (node >> 3) & 3;
  int j = node & 7;
  int t3 = f >> 4;
  int m = f & 15;
  return chunk * CHE + t3 * 2048 + ks * 512 + (m + 16 * q) * 8 + j;
}

__global__ void k_zero(uint4* __restrict__ p, int n) {
  int i = blockIdx.x * 256 + threadIdx.x;
  if (i < n) p[i] = make_uint4(0u, 0u, 0u, 0u);
}

__global__ void k_cast(const float* __restrict__ adj, unsigned short* __restrict__ adjb) {
  int col = (blockIdx.x * 256 + threadIdx.x) * 4;
  int row = blockIdx.y;
  float4 v = make_float4(0.f, 0.f, 0.f, 0.f);
  if (col < NN) v = *(const float4*)(adj + (size_t)row * NN + col);
  uint2 o;
  o.x = (unsigned)f2bf(v.x) | ((unsigned)f2bf(v.y) << 16);
  o.y = (unsigned)f2bf(v.z) | ((unsigned)f2bf(v.w) << 16);
  *(uint2*)(adjb + (size_t)row * NP + col) = o;
}

__global__ void k_initx0(const float* __restrict__ in, float* __restrict__ xf,
                         unsigned short* __restrict__ xb) {
  int n = blockIdx.x * 256 + threadIdx.x;
  if (n >= NP) return;
  float v = (n < NN) ? in[(size_t)n * TT] : 0.f;
  xf[n] = v;
  xb[flatXF(0, n)] = f2bf(v);
}

// C^T[f 0..47][node] = sum_k rhs^T[f][k] * A[node][k]
// 512 threads = 8 waves, ALL consumers; wave w owns K slice [w*640, w*640+640).
// No __syncthreads in K loop; cross-wave reduction via LDS at the end.
// EPI: 0 = store x1 (f32 row-major + bf16 frag); 1 = gate; 2 = candidate.
template <int EPI, bool USEBF>
__global__ __launch_bounds__(512, 2) void k_gemm(
    const unsigned short* __restrict__ adjb, const float* __restrict__ adjf,
    const unsigned short* __restrict__ rhs,
    float* __restrict__ outF, unsigned short* __restrict__ outB,
    const float* __restrict__ s0F, const float* __restrict__ s1F,
    const float* __restrict__ W, const float* __restrict__ bias,
    float* __restrict__ hT, float* __restrict__ uT,
    float* __restrict__ xoF, unsigned short* __restrict__ xoB,
    const float* __restrict__ inp, const float* __restrict__ Wp,
    const float* __restrict__ bp, float* __restrict__ dout,
    int mode, int tnext, int dstep) {
  constexpr int WC = (EPI == 1) ? 64 : 32;
  __shared__ float Pv[8 * FP * BN];                    // 24 KB partials
  __shared__ float x2s[(EPI > 0) ? FP * 17 : 1];
  __shared__ float Ws[(EPI > 0) ? DN * WC : 1];

  const int tid = threadIdx.x;
  const int wave = tid >> 6;
  const int lane = tid & 63;
  const int m = lane & 15;
  const int q = lane >> 4;
  const int nodeBase = blockIdx.x * BN;
  const int gn = nodeBase + m;
  const size_t ar = (size_t)((gn < NN) ? gn : NN - 1);

  if constexpr (EPI > 0) {
    for (int i = tid; i < DN * WC; i += 512) Ws[i] = W[i];
  }

  f32x4 acc[3] = {};
  short8 cb[2][4];
  short8 cx[2][12];

  auto loadA = [&](int i, short8* b) {
    const int k0 = (wave * CPW + i) * KC;
    if constexpr (USEBF) {
      const unsigned short* a0 = adjb + ar * NP + k0 + q * 8;
#pragma unroll
      for (int ks = 0; ks < 4; ++ks) b[ks] = *(const short8*)(a0 + ks * 32);
    } else {
      const float* a0 = adjf + ar * NN;
#pragma unroll
      for (int ks = 0; ks < 4; ++ks) {
        int kb = k0 + ks * 32 + q * 8;
        union { short8 s; unsigned short u[8]; } p0;
        if (kb + 8 <= NN) {
          float4 x0 = *(const float4*)(a0 + kb);
          float4 x1 = *(const float4*)(a0 + kb + 4);
          p0.u[0] = f2bf(x0.x); p0.u[1] = f2bf(x0.y); p0.u[2] = f2bf(x0.z); p0.u[3] = f2bf(x0.w);
          p0.u[4] = f2bf(x1.x); p0.u[5] = f2bf(x1.y); p0.u[6] = f2bf(x1.z); p0.u[7] = f2bf(x1.w);
        } else {
          for (int j = 0; j < 8; ++j) {
            int k = kb + j;
            p0.u[j] = (k < NN) ? f2bf(a0[k]) : (unsigned short)0;
          }
        }
        b[ks] = p0.s;
      }
    }
  };
  auto loadX = [&](int i, short8* x) {
    const unsigned short* xb = rhs + (size_t)(wave * CPW + i) * CHE + lane * 8;
#pragma unroll
    for (int t3 = 0; t3 < 3; ++t3)
#pragma unroll
      for (int ks = 0; ks < 4; ++ks)
        x[t3 * 4 + ks] = *(const short8*)(xb + t3 * 2048 + ks * 512);
  };

  loadA(0, cb[0]);
  loadX(0, cx[0]);
#pragma unroll
  for (int i = 0; i < CPW; ++i) {
    const int cur = i & 1, nxt = cur ^ 1;
    if (i + 1 < CPW) { loadA(i + 1, cb[nxt]); loadX(i + 1, cx[nxt]); }
#pragma unroll
    for (int ks = 0; ks < 4; ++ks)
#pragma unroll
      for (int t3 = 0; t3 < 3; ++t3)
        acc[t3] = __builtin_amdgcn_mfma_f32_16x16x32_bf16(cx[cur][t3 * 4 + ks],
                                                          cb[cur][ks], acc[t3], 0, 0, 0);
  }

#pragma unroll
  for (int t3 = 0; t3 < 3; ++t3)
#pragma unroll
    for (int r = 0; r < 4; ++r)
      Pv[wave * (FP * BN) + (t3 * 16 + q * 4 + r) * BN + m] = acc[t3][r];
  __syncthreads();

  if constexpr (EPI == 0) {
    for (int e = tid; e < FP * BN; e += 512) {
      int f = e >> 4, n = e & 15;
      float v = 0.f;
#pragma unroll
      for (int w = 0; w < 8; ++w) v += Pv[w * (FP * BN) + e];
      int gn2 = nodeBase + n;
      if (gn2 >= NN) v = 0.f;
      outF[(size_t)f * NP + gn2] = v;
      outB[flatXF(f, gn2)] = f2bf(v);
    }
  } else {
    for (int e = tid; e < FP * BN; e += 512) {
      int f = e >> 4, n = e & 15;
      float v = 0.f;
#pragma unroll
      for (int w = 0; w < 8; ++w) v += Pv[w * (FP * BN) + e];
      x2s[f * 17 + n] = v;
    }
    __syncthreads();
    const int nl = tid & 15;
    const int cg = tid >> 4;  // 0..31
    const int gn2 = nodeBase + nl;
    const bool valid = gn2 < NN;
    const int gnc = valid ? gn2 : NN - 1;
    if constexpr (EPI == 1) {
      float a0 = bias[cg], a1 = bias[cg + 32];
      for (int f = 0; f < FR; ++f) {
        float fe = s0F[(size_t)f * NP + gnc];
        a0 += fe * Ws[f * WC + cg]; a1 += fe * Ws[f * WC + cg + 32];
      }
      for (int f = 0; f < FR; ++f) {
        float fe = s1F[(size_t)f * NP + gnc];
        a0 += fe * Ws[(FR + f) * WC + cg]; a1 += fe * Ws[(FR + f) * WC + cg + 32];
      }
      for (int f = 0; f < FR; ++f) {
        float fe = x2s[f * 17 + nl];
        a0 += fe * Ws[(2 * FR + f) * WC + cg]; a1 += fe * Ws[(2 * FR + f) * WC + cg + 32];
      }
      float r = 1.f / (1.f + expf(-a0));          // r gate (cols 0..31)
      float hv = hT[(size_t)cg * NP + gnc];
      float xc = valid ? r * hv : 0.f;
      xoF[(size_t)(1 + cg) * NP + gn2] = xc;
      xoB[flatXF(1 + cg, gn2)] = f2bf(xc);
      float u = 1.f / (1.f + expf(-a1));          // u gate (cols 32..63)
      uT[(size_t)cg * NP + gn2] = valid ? u : 0.f;
      if (tid < BN) {
        int g3 = nodeBase + tid;
        float v0 = s0F[g3];
        xoF[g3] = v0;
        xoB[flatXF(0, g3)] = f2bf(v0);
      }
    } else {
      float a0 = bias[cg];
      for (int f = 0; f < FR; ++f) a0 += s0F[(size_t)f * NP + gnc] * Ws[f * WC + cg];
      for (int f = 0; f < FR; ++f) a0 += s1F[(size_t)f * NP + gnc] * Ws[(FR + f) * WC + cg];
      for (int f = 0; f < FR; ++f) a0 += x2s[f * 17 + nl] * Ws[(2 * FR + f) * WC + cg];
      float c = tanhf(a0);
      float u = uT[(size_t)cg * NP + gnc];
      float h0 = hT[(size_t)cg * NP + gnc];
      float hn = u * h0 + (1.f - u) * c;
      float hw = valid ? hn : 0.f;
      hT[(size_t)cg * NP + gn2] = hw;
      xoF[(size_t)(1 + cg) * NP + gn2] = hw;
      xoB[flatXF(1 + cg, gn2)] = f2bf(hw);
      __syncthreads();            // all x2s reads done
      x2s[cg * 17 + nl] = hw;     // reuse as h scratch
      __syncthreads();
      if (tid < BN) {
        int g3 = nodeBase + tid;
        bool v3 = g3 < NN;
        float x0 = 0.f;
        if (mode == 0) {
          x0 = v3 ? inp[(size_t)g3 * TT + tnext] : 0.f;
        } else if (mode == 2) {
          float p = bp[0];
          for (int j = 0; j < UU; ++j) p += x2s[j * 17 + tid] * Wp[j];
          if (v3) dout[(size_t)g3 * TT + dstep] = p;
          x0 = v3 ? p : 0.f;
        }
        xoF[g3] = x0;
        xoB[flatXF(0, g3)] = f2bf(x0);
      }
    }
  }
}

extern "C" void kernel_launch(void* const* d_in, const int* in_sizes, int n_in,
                              void* d_out, int out_size, void* d_ws, size_t ws_size,
                              hipStream_t stream) {
  const float* inputs = (const float*)d_in[0];
  const float* adj = (const float*)d_in[2];
  const float* eWg = (const float*)d_in[3];
  const float* eBg = (const float*)d_in[4];
  const float* eWc = (const float*)d_in[5];
  const float* eBc = (const float*)d_in[6];
  const float* dWg = (const float*)d_in[7];
  const float* dBg = (const float*)d_in[8];
  const float* dWc = (const float*)d_in[9];
  const float* dBc = (const float*)d_in[10];
  const float* Wp = (const float*)d_in[11];
  const float* bp = (const float*)d_in[12];
  float* dout = (float*)d_out;

  char* ws = (char*)d_ws;
  size_t o = 0;
  float* xhGf = (float*)(ws + o); o += (size_t)FP * NP * 4;
  unsigned short* xhGb = (unsigned short*)(ws + o); o += (size_t)FP * NP * 2;
  float* xhCf = (float*)(ws + o); o += (size_t)FP * NP * 4;
  unsigned short* xhCb = (unsigned short*)(ws + o); o += (size_t)FP * NP * 2;
  float* x1f = (float*)(ws + o); o += (size_t)FP * NP * 4;
  unsigned short* x1b = (unsigned short*)(ws + o); o += (size_t)FP * NP * 2;
  float* hT = (float*)(ws + o); o += (size_t)UU * NP * 4;
  float* uT = (float*)(ws + o); o += (size_t)UU * NP * 4;
  size_t small = o;
  unsigned short* adjb = (unsigned short*)(ws + o);
  size_t need = o + (size_t)NN * NP * 2;
  bool usebf = ws_size >= need;

  k_zero<<<(int)(small / 16 / 256), 256, 0, stream>>>((uint4*)ws, (int)(small / 16));
  if (usebf) k_cast<<<dim3(5, NN), 256, 0, stream>>>(adj, adjb);
  k_initx0<<<NP / 256, 256, 0, stream>>>(inputs, xhGf, xhGb);

  auto run = [&](auto ubc) {
    constexpr bool UB = decltype(ubc)::value;
    const unsigned short* ab = UB ? adjb : nullptr;
    for (int t = 0; t < 2 * TT; ++t) {
      bool enc = t < TT;
      const float* Wg = enc ? eWg : dWg;
      const float* Bg = enc ? eBg : dBg;
      const float* Wc = enc ? eWc : dWc;
      const float* Bc = enc ? eBc : dBc;
      int mode, tn = 0, ds = 0;
      if (t < TT - 1) { mode = 0; tn = t + 1; }
      else if (t == TT - 1) { mode = 1; }
      else { mode = 2; ds = t - TT; }

      // K1: x1_g = A @ xh_g
      k_gemm<0, UB><<<GRID_MM, 512, 0, stream>>>(
          ab, adj, xhGb, x1f, x1b,
          nullptr, nullptr, nullptr, nullptr, nullptr, nullptr,
          nullptr, nullptr, nullptr, nullptr, nullptr, nullptr, 0, 0, 0);
      // K2: x2_g = A @ x1_g ; gate epilogue -> xh_c, u
      k_gemm<1, UB><<<GRID_MM, 512, 0, stream>>>(
          ab, adj, x1b, nullptr, nullptr,
          xhGf, x1f, Wg, Bg, hT, uT, xhCf, xhCb,
          nullptr, nullptr, nullptr, nullptr, 0, 0, 0);
      // K3: x1_c = A @ xh_c
      k_gemm<0, UB><<<GRID_MM, 512, 0, stream>>>(
          ab, adj, xhCb, x1f, x1b,
          nullptr, nullptr, nullptr, nullptr, nullptr, nullptr,
          nullptr, nullptr, nullptr, nullptr, nullptr, nullptr, 0, 0, 0);
      // K4: x2_c = A @ x1_c ; candidate epilogue -> h, next xh_g (+ projection)
      k_gemm<2, UB><<<GRID_MM, 512, 0, stream>>>(
          ab, adj, x1b, nullptr, nullptr,
          xhCf, x1f, Wc, Bc, hT, uT, xhGf, xhGb,
          inputs, Wp, bp, dout, mode, tn, ds);
    }
  };
  if (usebf) run(std::integral_constant<bool, true>{});
  else run(std::integral_constant<bool, false>{});
}

// Round 5
// 2462.711 us; speedup vs baseline: 2.9008x; 1.0125x over previous
//
#include <hip/hip_runtime.h>
#include <type_traits>

constexpr int NN = 5000;   // nodes
constexpr int NP = 5120;   // padded nodes / K
constexpr int TT = 12;     // enc/dec length
constexpr int UU = 32;     // rnn units
constexpr int FP = 48;     // padded feature rows
constexpr int FR = 33;     // real feature rows (IN+U)
constexpr int DN = 99;     // DIN
constexpr int BN = 16;     // nodes per block
constexpr int KC = 128;    // K chunk
constexpr int NKC = NP / KC;                 // 40
constexpr int CPW = NKC / 8;                 // 5 chunks per wave (8-way K split)
constexpr int GRID_MM = (NN + BN - 1) / BN;  // 313
constexpr int CHE = FP * KC;                 // 6144 elements per chunk (frag layout)

typedef __attribute__((ext_vector_type(8))) short short8;
typedef __attribute__((ext_vector_type(4))) float f32x4;

__device__ __forceinline__ unsigned short f2bf(float x) {
  union { float f; unsigned u; } c; c.f = x;
  return (unsigned short)((c.u + 0x7FFFu + ((c.u >> 16) & 1u)) >> 16);
}

// MFMA A-fragment layout for X^T: element (f, node-as-K) -> flat index such
// that a wave's 16B load at base+lane*16 is fully coalesced.
__device__ __forceinline__ int flatXF(int f, int node) {
  int chunk = node >> 7;
  int ks = (node >> 5) & 3;
  int q = (node >> 3) & 3;
  int j = node & 7;
  int t3 = f >> 4;
  int m = f & 15;
  return chunk * CHE + t3 * 2048 + ks * 512 + (m + 16 * q) * 8 + j;
}

__global__ void k_zero(uint4* __restrict__ p, int n) {
  int i = blockIdx.x * 256 + threadIdx.x;
  if (i < n) p[i] = make_uint4(0u, 0u, 0u, 0u);
}

__global__ void k_cast(const float* __restrict__ adj, unsigned short* __restrict__ adjb) {
  int col = (blockIdx.x * 256 + threadIdx.x) * 4;
  int row = blockIdx.y;
  float4 v = make_float4(0.f, 0.f, 0.f, 0.f);
  if (col < NN) v = *(const float4*)(adj + (size_t)row * NN + col);
  uint2 o;
  o.x = (unsigned)f2bf(v.x) | ((unsigned)f2bf(v.y) << 16);
  o.y = (unsigned)f2bf(v.z) | ((unsigned)f2bf(v.w) << 16);
  *(uint2*)(adjb + (size_t)row * NP + col) = o;
}

__global__ void k_initx0(const float* __restrict__ in, float* __restrict__ xf,
                         unsigned short* __restrict__ xb) {
  int n = blockIdx.x * 256 + threadIdx.x;
  if (n >= NP) return;
  float v = (n < NN) ? in[(size_t)n * TT] : 0.f;
  xf[n] = v;
  xb[flatXF(0, n)] = f2bf(v);
}

// C^T[f 0..47][node] = sum_k rhs^T[f][k] * A[node][k]
// 512 threads = 8 waves, ALL consumers; wave w owns K slice [w*640, +640).
// K-loop: A double-buffered, X single-buffered (fits 128-VGPR budget so
// __launch_bounds__(512,4) gives 2 blocks/CU = 16 waves/CU).
// EPI: 0 = store x1 (f32 row-major + bf16 frag); 1 = gate; 2 = candidate.
template <int EPI, bool USEBF>
__global__ __launch_bounds__(512, 4) void k_gemm(
    const unsigned short* __restrict__ adjb, const float* __restrict__ adjf,
    const unsigned short* __restrict__ rhs,
    float* __restrict__ outF, unsigned short* __restrict__ outB,
    const float* __restrict__ s0F, const float* __restrict__ s1F,
    const float* __restrict__ W, const float* __restrict__ bias,
    float* __restrict__ hT, float* __restrict__ uT,
    float* __restrict__ xoF, unsigned short* __restrict__ xoB,
    const float* __restrict__ inp, const float* __restrict__ Wp,
    const float* __restrict__ bp, float* __restrict__ dout,
    int mode, int tnext, int dstep) {
  constexpr int WC = (EPI == 1) ? 64 : 32;
  __shared__ float Pv[8 * FP * BN];                    // 24 KB partials
  __shared__ float x2s[(EPI > 0) ? FP * 17 : 1];
  __shared__ float Ws[(EPI > 0) ? DN * WC : 1];

  const int tid = threadIdx.x;
  const int wave = tid >> 6;
  const int lane = tid & 63;
  const int m = lane & 15;
  const int q = lane >> 4;
  const int nodeBase = blockIdx.x * BN;
  const int gn = nodeBase + m;
  const size_t ar = (size_t)((gn < NN) ? gn : NN - 1);

  f32x4 acc0 = {}, acc1 = {}, acc2 = {};
  short8 aCur[4], aNxt[4];

  auto loadA = [&](int i, short8* b) {
    const int k0 = (wave * CPW + i) * KC;
    if constexpr (USEBF) {
      const unsigned short* a0 = adjb + ar * NP + k0 + q * 8;
#pragma unroll
      for (int ks = 0; ks < 4; ++ks) b[ks] = *(const short8*)(a0 + ks * 32);
    } else {
      const float* a0 = adjf + ar * NN;
#pragma unroll
      for (int ks = 0; ks < 4; ++ks) {
        int kb = k0 + ks * 32 + q * 8;
        union { short8 s; unsigned short u[8]; } p0;
        if (kb + 8 <= NN) {
          float4 x0 = *(const float4*)(a0 + kb);
          float4 x1 = *(const float4*)(a0 + kb + 4);
          p0.u[0] = f2bf(x0.x); p0.u[1] = f2bf(x0.y); p0.u[2] = f2bf(x0.z); p0.u[3] = f2bf(x0.w);
          p0.u[4] = f2bf(x1.x); p0.u[5] = f2bf(x1.y); p0.u[6] = f2bf(x1.z); p0.u[7] = f2bf(x1.w);
        } else {
          for (int j = 0; j < 8; ++j) {
            int k = kb + j;
            p0.u[j] = (k < NN) ? f2bf(a0[k]) : (unsigned short)0;
          }
        }
        b[ks] = p0.s;
      }
    }
  };

  loadA(0, aCur);
#pragma unroll
  for (int i = 0; i < CPW; ++i) {
    if (i + 1 < CPW) loadA(i + 1, aNxt);
    const int ch = wave * CPW + i;
    short8 cx[12];
    const unsigned short* xb = rhs + (size_t)ch * CHE + lane * 8;
#pragma unroll
    for (int t3 = 0; t3 < 3; ++t3)
#pragma unroll
      for (int ks = 0; ks < 4; ++ks)
        cx[t3 * 4 + ks] = *(const short8*)(xb + t3 * 2048 + ks * 512);
#pragma unroll
    for (int ks = 0; ks < 4; ++ks) {
      acc0 = __builtin_amdgcn_mfma_f32_16x16x32_bf16(cx[ks], aCur[ks], acc0, 0, 0, 0);
      acc1 = __builtin_amdgcn_mfma_f32_16x16x32_bf16(cx[4 + ks], aCur[ks], acc1, 0, 0, 0);
      acc2 = __builtin_amdgcn_mfma_f32_16x16x32_bf16(cx[8 + ks], aCur[ks], acc2, 0, 0, 0);
    }
#pragma unroll
    for (int ks = 0; ks < 4; ++ks) aCur[ks] = aNxt[ks];
  }

  // stage epilogue weights AFTER the K loop: loads hide under Pv reduce
  if constexpr (EPI > 0) {
    for (int i = tid; i < DN * WC; i += 512) Ws[i] = W[i];
  }

#pragma unroll
  for (int r = 0; r < 4; ++r) {
    Pv[wave * (FP * BN) + (q * 4 + r) * BN + m] = acc0[r];
    Pv[wave * (FP * BN) + (16 + q * 4 + r) * BN + m] = acc1[r];
    Pv[wave * (FP * BN) + (32 + q * 4 + r) * BN + m] = acc2[r];
  }
  __syncthreads();

  if constexpr (EPI == 0) {
    for (int e = tid; e < FP * BN; e += 512) {
      int f = e >> 4, n = e & 15;
      float v = 0.f;
#pragma unroll
      for (int w = 0; w < 8; ++w) v += Pv[w * (FP * BN) + e];
      int gn2 = nodeBase + n;
      if (gn2 >= NN) v = 0.f;
      outF[(size_t)f * NP + gn2] = v;
      outB[flatXF(f, gn2)] = f2bf(v);
    }
  } else {
    for (int e = tid; e < FP * BN; e += 512) {
      int f = e >> 4, n = e & 15;
      float v = 0.f;
#pragma unroll
      for (int w = 0; w < 8; ++w) v += Pv[w * (FP * BN) + e];
      x2s[f * 17 + n] = v;
    }
    __syncthreads();
    const int nl = tid & 15;
    const int cg = tid >> 4;  // 0..31
    const int gn2 = nodeBase + nl;
    const bool valid = gn2 < NN;
    const int gnc = valid ? gn2 : NN - 1;
    if constexpr (EPI == 1) {
      float a0 = bias[cg], a1 = bias[cg + 32];
      for (int f = 0; f < FR; ++f) {
        float fe = s0F[(size_t)f * NP + gnc];
        a0 += fe * Ws[f * WC + cg]; a1 += fe * Ws[f * WC + cg + 32];
      }
      for (int f = 0; f < FR; ++f) {
        float fe = s1F[(size_t)f * NP + gnc];
        a0 += fe * Ws[(FR + f) * WC + cg]; a1 += fe * Ws[(FR + f) * WC + cg + 32];
      }
      for (int f = 0; f < FR; ++f) {
        float fe = x2s[f * 17 + nl];
        a0 += fe * Ws[(2 * FR + f) * WC + cg]; a1 += fe * Ws[(2 * FR + f) * WC + cg + 32];
      }
      float r = 1.f / (1.f + expf(-a0));          // r gate (cols 0..31)
      float hv = hT[(size_t)cg * NP + gnc];
      float xc = valid ? r * hv : 0.f;
      xoF[(size_t)(1 + cg) * NP + gn2] = xc;
      xoB[flatXF(1 + cg, gn2)] = f2bf(xc);
      float u = 1.f / (1.f + expf(-a1));          // u gate (cols 32..63)
      uT[(size_t)cg * NP + gn2] = valid ? u : 0.f;
      if (tid < BN) {
        int g3 = nodeBase + tid;
        float v0 = s0F[g3];
        xoF[g3] = v0;
        xoB[flatXF(0, g3)] = f2bf(v0);
      }
    } else {
      float a0 = bias[cg];
      for (int f = 0; f < FR; ++f) a0 += s0F[(size_t)f * NP + gnc] * Ws[f * WC + cg];
      for (int f = 0; f < FR; ++f) a0 += s1F[(size_t)f * NP + gnc] * Ws[(FR + f) * WC + cg];
      for (int f = 0; f < FR; ++f) a0 += x2s[f * 17 + nl] * Ws[(2 * FR + f) * WC + cg];
      float c = tanhf(a0);
      float u = uT[(size_t)cg * NP + gnc];
      float h0 = hT[(size_t)cg * NP + gnc];
      float hn = u * h0 + (1.f - u) * c;
      float hw = valid ? hn : 0.f;
      hT[(size_t)cg * NP + gn2] = hw;
      xoF[(size_t)(1 + cg) * NP + gn2] = hw;
      xoB[flatXF(1 + cg, gn2)] = f2bf(hw);
      __syncthreads();            // all x2s reads done
      x2s[cg * 17 + nl] = hw;     // reuse as h scratch
      __syncthreads();
      if (tid < BN) {
        int g3 = nodeBase + tid;
        bool v3 = g3 < NN;
        float x0 = 0.f;
        if (mode == 0) {
          x0 = v3 ? inp[(size_t)g3 * TT + tnext] : 0.f;
        } else if (mode == 2) {
          float p = bp[0];
          for (int j = 0; j < UU; ++j) p += x2s[j * 17 + tid] * Wp[j];
          if (v3) dout[(size_t)g3 * TT + dstep] = p;
          x0 = v3 ? p : 0.f;
        }
        xoF[g3] = x0;
        xoB[flatXF(0, g3)] = f2bf(x0);
      }
    }
  }
}

extern "C" void kernel_launch(void* const* d_in, const int* in_sizes, int n_in,
                              void* d_out, int out_size, void* d_ws, size_t ws_size,
                              hipStream_t stream) {
  const float* inputs = (const float*)d_in[0];
  const float* adj = (const float*)d_in[2];
  const float* eWg = (const float*)d_in[3];
  const float* eBg = (const float*)d_in[4];
  const float* eWc = (const float*)d_in[5];
  const float* eBc = (const float*)d_in[6];
  const float* dWg = (const float*)d_in[7];
  const float* dBg = (const float*)d_in[8];
  const float* dWc = (const float*)d_in[9];
  const float* dBc = (const float*)d_in[10];
  const float* Wp = (const float*)d_in[11];
  const float* bp = (const float*)d_in[12];
  float* dout = (float*)d_out;

  char* ws = (char*)d_ws;
  size_t o = 0;
  float* xhGf = (float*)(ws + o); o += (size_t)FP * NP * 4;
  unsigned short* xhGb = (unsigned short*)(ws + o); o += (size_t)FP * NP * 2;
  float* xhCf = (float*)(ws + o); o += (size_t)FP * NP * 4;
  unsigned short* xhCb = (unsigned short*)(ws + o); o += (size_t)FP * NP * 2;
  float* x1f = (float*)(ws + o); o += (size_t)FP * NP * 4;
  unsigned short* x1b = (unsigned short*)(ws + o); o += (size_t)FP * NP * 2;
  float* hT = (float*)(ws + o); o += (size_t)UU * NP * 4;
  float* uT = (float*)(ws + o); o += (size_t)UU * NP * 4;
  size_t small = o;
  unsigned short* adjb = (unsigned short*)(ws + o);
  size_t need = o + (size_t)NN * NP * 2;
  bool usebf = ws_size >= need;

  k_zero<<<(int)((small / 16 + 255) / 256), 256, 0, stream>>>((uint4*)ws, (int)(small / 16));
  if (usebf) k_cast<<<dim3(5, NN), 256, 0, stream>>>(adj, adjb);
  k_initx0<<<NP / 256, 256, 0, stream>>>(inputs, xhGf, xhGb);

  auto run = [&](auto ubc) {
    constexpr bool UB = decltype(ubc)::value;
    const unsigned short* ab = UB ? adjb : nullptr;
    for (int t = 0; t < 2 * TT; ++t) {
      bool enc = t < TT;
      const float* Wg = enc ? eWg : dWg;
      const float* Bg = enc ? eBg : dBg;
      const float* Wc = enc ? eWc : dWc;
      const float* Bc = enc ? eBc : dBc;
      int mode, tn = 0, ds = 0;
      if (t < TT - 1) { mode = 0; tn = t + 1; }
      else if (t == TT - 1) { mode = 1; }
      else { mode = 2; ds = t - TT; }

      // K1: x1_g = A @ xh_g
      k_gemm<0, UB><<<GRID_MM, 512, 0, stream>>>(
          ab, adj, xhGb, x1f, x1b,
          nullptr, nullptr, nullptr, nullptr, nullptr, nullptr,
          nullptr, nullptr, nullptr, nullptr, nullptr, nullptr, 0, 0, 0);
      // K2: x2_g = A @ x1_g ; gate epilogue -> xh_c, u
      k_gemm<1, UB><<<GRID_MM, 512, 0, stream>>>(
          ab, adj, x1b, nullptr, nullptr,
          xhGf, x1f, Wg, Bg, hT, uT, xhCf, xhCb,
          nullptr, nullptr, nullptr, nullptr, 0, 0, 0);
      // K3: x1_c = A @ xh_c
      k_gemm<0, UB><<<GRID_MM, 512, 0, stream>>>(
          ab, adj, xhCb, x1f, x1b,
          nullptr, nullptr, nullptr, nullptr, nullptr, nullptr,
          nullptr, nullptr, nullptr, nullptr, nullptr, nullptr, 0, 0, 0);
      // K4: x2_c = A @ x1_c ; candidate epilogue -> h, next xh_g (+ projection)
      k_gemm<2, UB><<<GRID_MM, 512, 0, stream>>>(
          ab, adj, x1b, nullptr, nullptr,
          xhCf, x1f, Wc, Bc, hT, uT, xhGf, xhGb,
          inputs, Wp, bp, dout, mode, tn, ds);
    }
  };
  if (usebf) run(std::integral_constant<bool, true>{});
  else run(std::integral_constant<bool, false>{});
}